// Round 3
// baseline (1630.029 us; speedup 1.0000x reference)
//
#include <hip/hip_runtime.h>

#define CDIM 128
#define KOFF 4
#define EPS 1e-4f
#define SCAN_CHUNK 2048   // 256 threads * 8 elems

typedef __attribute__((ext_vector_type(8))) short bf16x8;
typedef __attribute__((ext_vector_type(4))) float f32x4;

__device__ __forceinline__ unsigned short f2bf(float f) {
    unsigned int u = __builtin_bit_cast(unsigned int, f);
    u += 0x7fffu + ((u >> 16) & 1u);          // round-to-nearest-even
    return (unsigned short)(u >> 16);
}

// LDS chunk-major slot swizzle: spreads 16B chunks so every wave phase is <=2-way
__device__ __forceinline__ int swzf(int c) { return ((c & 3) << 1) ^ ((c >> 2) & 1); }

// ---------------------------------------------------------------------------
// W convert+transpose: Wt[k][cout][cin] = bf16(W[k][cin][cout])
// ---------------------------------------------------------------------------
__global__ __launch_bounds__(256) void wconv_kernel(
    const float* __restrict__ W1, const float* __restrict__ W2,
    short* __restrict__ W1t, short* __restrict__ W2t)
{
    int idx = blockIdx.x * 256 + threadIdx.x;       // [k][co][ci]
    if (idx >= KOFF * CDIM * CDIM) return;
    int ci = idx & (CDIM - 1);
    int co = (idx >> 7) & (CDIM - 1);
    int k  = idx >> 14;
    size_t src = (size_t)k * CDIM * CDIM + (size_t)ci * CDIM + co;
    W1t[idx] = (short)f2bf(W1[src]);
    W2t[idx] = (short)f2bf(W2[src]);
}

// ---------------------------------------------------------------------------
// Rulebook build: count -> scan -> fill.  Entry = src | (jloc<<19), jloc=j&63.
// ---------------------------------------------------------------------------
__global__ __launch_bounds__(256) void count_kernel(
    const int* __restrict__ out_idx, const int* __restrict__ mask,
    int* __restrict__ cnt, int n, int KN)
{
    int t = blockIdx.x * 256 + threadIdx.x;
    if (t >= KN) return;
    if (mask[t]) {
        int k = t / n;
        atomicAdd(&cnt[(size_t)k * n + out_idx[t]], 1);
    }
}

__global__ __launch_bounds__(256) void scan_p1(
    const int* __restrict__ in, int* __restrict__ bsum, int L)
{
    __shared__ int red[256];
    int base = blockIdx.x * SCAN_CHUNK;
    int s = 0;
    #pragma unroll
    for (int u = 0; u < 8; ++u) {
        int i = base + u * 256 + threadIdx.x;
        if (i < L) s += in[i];
    }
    red[threadIdx.x] = s;
    __syncthreads();
    for (int d = 128; d > 0; d >>= 1) {
        if (threadIdx.x < d) red[threadIdx.x] += red[threadIdx.x + d];
        __syncthreads();
    }
    if (threadIdx.x == 0) bsum[blockIdx.x] = red[0];
}

__global__ __launch_bounds__(1024) void scan_p2(int* __restrict__ bsum, int NB)
{
    __shared__ int s[1024];
    int t = threadIdx.x;
    s[t] = (t < NB) ? bsum[t] : 0;
    __syncthreads();
    for (int d = 1; d < 1024; d <<= 1) {
        int x = s[t];
        if (t >= d) x += s[t - d];
        __syncthreads();
        s[t] = x;
        __syncthreads();
    }
    if (t < NB) bsum[t] = (t == 0) ? 0 : s[t - 1];   // exclusive
}

__global__ __launch_bounds__(256) void scan_p3(
    const int* __restrict__ in, const int* __restrict__ bsum,
    int* __restrict__ out, int L)
{
    __shared__ int ts[256];
    int t = threadIdx.x;
    int base = blockIdx.x * SCAN_CHUNK + t * 8;
    int v[8]; int s = 0;
    #pragma unroll
    for (int u = 0; u < 8; ++u) {
        int i = base + u;
        v[u] = (i < L) ? in[i] : 0;
        s += v[u];
    }
    ts[t] = s;
    __syncthreads();
    for (int d = 1; d < 256; d <<= 1) {
        int x = ts[t];
        if (t >= d) x += ts[t - d];
        __syncthreads();
        ts[t] = x;
        __syncthreads();
    }
    int pre = bsum[blockIdx.x] + ((t == 0) ? 0 : ts[t - 1]);
    #pragma unroll
    for (int u = 0; u < 8; ++u) {
        int i = base + u;
        if (i < L) { out[i] = pre; pre += v[u]; }
    }
}

__global__ __launch_bounds__(256) void fill_kernel(
    const int* __restrict__ out_idx, const int* __restrict__ in_idx,
    const int* __restrict__ mask, int* __restrict__ off,
    int* __restrict__ ent, int n, int KN)
{
    int t = blockIdx.x * 256 + threadIdx.x;
    if (t >= KN) return;
    if (mask[t]) {
        int k = t / n;
        int j = out_idx[t];
        int pos = atomicAdd(&off[(size_t)k * n + j], 1);
        ent[pos] = in_idx[t] | ((j & 63) << 19);
    }
}
// post-fill invariant: off[x] == original exclusive-scan off[x+1]
// => start of bucket x = (x==0) ? 0 : off[x-1]

// ---------------------------------------------------------------------------
// CSR conv: block owns 64 OUTPUT rows. For each k: W[k]-fragments in VGPRs,
// gather 32-entry chunks into LDS, MFMA, ds_add scatter into LDS out-tile,
// fused BN epilogue.  EPI=0: BN1+ReLU -> bf16 h1b.  EPI=1: BN2+residual -> f32.
// ---------------------------------------------------------------------------
template <int EPI>
__global__ __launch_bounds__(256) void conv_csr_kernel(
    const void* __restrict__ Xv,          // EPI0: f32 [n][128]; EPI1: bf16
    const short* __restrict__ Wt,         // [4][cout][cin] bf16
    const int* __restrict__ off,          // post-fill offsets
    const int* __restrict__ ent,
    const float* __restrict__ gamma, const float* __restrict__ beta,
    const float* __restrict__ mean, const float* __restrict__ var,
    const float* __restrict__ feat,       // residual (EPI1)
    void* __restrict__ Yv, int n)
{
    const int j0 = blockIdx.x * 64;
    const int t  = threadIdx.x;

    __shared__ alignas(16) short As[16 * 32 * 8];   // 8 KB  [c][slot][8]
    __shared__ float Ot[64 * 128];                  // 32 KB out-tile
    __shared__ alignas(16) float s_scale[CDIM], s_shift[CDIM];
    __shared__ int s_jloc[32];

    if (t < CDIM) {
        float sc = gamma[t] * rsqrtf(var[t] + EPS);
        s_scale[t] = sc;
        s_shift[t] = beta[t] - mean[t] * sc;
    }
    {
        float4 z = make_float4(0.f, 0.f, 0.f, 0.f);
        #pragma unroll
        for (int u = 0; u < 8; ++u) ((float4*)Ot)[u * 256 + t] = z;
    }

    const int jend = min(j0 + 64, n);
    const int w    = t >> 6;
    const int lane = t & 63;
    const int lrow = lane & 15;
    const int g    = lane >> 4;
    const int strip = w & 1;          // entry strip (rows strip*16..+15)
    const int nth   = (w >> 1) * 4;   // cout tiles nth..nth+3

    for (int k = 0; k < KOFF; ++k) {
        // B fragments for this wave's cout-half, held in VGPRs for all chunks
        const short* Wk = Wt + (size_t)k * CDIM * CDIM;
        bf16x8 bfr[4][4];
        #pragma unroll
        for (int nt = 0; nt < 4; ++nt)
            #pragma unroll
            for (int kk = 0; kk < 4; ++kk) {
                int brow = (nth + nt) * 16 + lrow;
                bfr[nt][kk] = *(const bf16x8*)(Wk + brow * CDIM + kk * 32 + g * 8);
            }

        size_t x0 = (size_t)k * n + j0;
        int e0 = (x0 == 0) ? 0 : off[x0 - 1];
        int e1 = off[(size_t)k * n + (jend - 1)];

        for (int c0 = e0; c0 < e1; c0 += 32) {
            __syncthreads();   // prev chunk's As reads done
            // ---- stage 32 entries into As (+ s_jloc) ----
            {
                int erow = t >> 3;          // 0..31
                int seg  = t & 7;
                int ei   = c0 + erow;
                int entv = (ei < e1) ? ent[ei] : -1;
                if (seg == 0) s_jloc[erow] = (entv >= 0) ? (entv >> 19) : 64;
                int src = entv & 0x7FFFF;
                #pragma unroll
                for (int u = 0; u < 2; ++u) {
                    int c    = u * 8 + seg;
                    int slot = erow ^ swzf(c);
                    bf16x8 v = {0, 0, 0, 0, 0, 0, 0, 0};
                    if (entv >= 0) {
                        if (EPI == 0) {
                            const float4* xr = (const float4*)Xv + (size_t)src * 32;
                            float4 a = xr[c * 2], b = xr[c * 2 + 1];
                            v[0] = (short)f2bf(a.x); v[1] = (short)f2bf(a.y);
                            v[2] = (short)f2bf(a.z); v[3] = (short)f2bf(a.w);
                            v[4] = (short)f2bf(b.x); v[5] = (short)f2bf(b.y);
                            v[6] = (short)f2bf(b.z); v[7] = (short)f2bf(b.w);
                        } else {
                            v = ((const bf16x8*)((const short*)Xv + (size_t)src * CDIM))[c];
                        }
                    }
                    *(bf16x8*)(As + (c << 8) + (slot << 3)) = v;
                }
            }
            __syncthreads();
            // ---- MFMA ----
            bf16x8 af[4];
            int arow = strip * 16 + lrow;
            #pragma unroll
            for (int kk = 0; kk < 4; ++kk) {
                int c = kk * 4 + g;
                af[kk] = *(const bf16x8*)(As + (c << 8) + ((arow ^ swzf(c)) << 3));
            }
            f32x4 acc[4];
            #pragma unroll
            for (int nt = 0; nt < 4; ++nt) acc[nt] = (f32x4){0.f, 0.f, 0.f, 0.f};
            #pragma unroll
            for (int nt = 0; nt < 4; ++nt)
                #pragma unroll
                for (int kk = 0; kk < 4; ++kk)
                    acc[nt] = __builtin_amdgcn_mfma_f32_16x16x32_bf16(
                        af[kk], bfr[nt][kk], acc[nt], 0, 0, 0);
            // ---- scatter into LDS out-tile ----
            #pragma unroll
            for (int jj = 0; jj < 4; ++jj) {
                int el = strip * 16 + g * 4 + jj;
                int jl = s_jloc[el];
                if (jl < 64) {
                    float* orow = Ot + jl * CDIM + nth * 16 + lrow;
                    #pragma unroll
                    for (int nt = 0; nt < 4; ++nt)
                        atomicAdd(orow + nt * 16, acc[nt][jj]);
                }
            }
        }
    }
    __syncthreads();

    // ---- fused BN epilogue, dense coalesced store ----
    const int jrows = jend - j0;
    #pragma unroll
    for (int u = 0; u < 8; ++u) {
        int idx = u * 256 + t;
        int row = idx >> 5, c4 = idx & 31;
        if (row < jrows) {
            float4 x  = ((const float4*)Ot)[idx];
            float4 sc = ((const float4*)s_scale)[c4];
            float4 sh = ((const float4*)s_shift)[c4];
            size_t go = (size_t)(j0 + row) * 32 + c4;
            if (EPI == 0) {
                ushort4 o;
                o.x = f2bf(fmaxf(x.x * sc.x + sh.x, 0.f));
                o.y = f2bf(fmaxf(x.y * sc.y + sh.y, 0.f));
                o.z = f2bf(fmaxf(x.z * sc.z + sh.z, 0.f));
                o.w = f2bf(fmaxf(x.w * sc.w + sh.w, 0.f));
                ((ushort4*)Yv)[go] = o;
            } else {
                float4 f = ((const float4*)feat)[go];
                float4 r;
                r.x = x.x * sc.x + sh.x + f.x;
                r.y = x.y * sc.y + sh.y + f.y;
                r.z = x.z * sc.z + sh.z + f.z;
                r.w = x.w * sc.w + sh.w + f.w;
                ((float4*)Yv)[go] = r;
            }
        }
    }
}

extern "C" void kernel_launch(void* const* d_in, const int* in_sizes, int n_in,
                              void* d_out, int out_size, void* d_ws, size_t ws_size,
                              hipStream_t stream)
{
    const float* feat   = (const float*)d_in[0];
    const float* W1     = (const float*)d_in[1];
    const float* W2     = (const float*)d_in[2];
    const float* gamma1 = (const float*)d_in[3];
    const float* beta1  = (const float*)d_in[4];
    const float* mean1  = (const float*)d_in[5];
    const float* var1   = (const float*)d_in[6];
    const float* gamma2 = (const float*)d_in[7];
    const float* beta2  = (const float*)d_in[8];
    const float* mean2  = (const float*)d_in[9];
    const float* var2   = (const float*)d_in[10];
    const int* in_idx   = (const int*)d_in[11];
    const int* out_idx  = (const int*)d_in[12];
    const int* mask     = (const int*)d_in[13];

    const int n  = in_sizes[0] / CDIM;     // 500000 (< 2^19 for entry packing)
    const int KN = KOFF * n;
    const int L  = KN + 1;
    const int NB = (L + SCAN_CHUNK - 1) / SCAN_CHUNK;   // 977 <= 1024

    auto alignup = [](size_t x) { return (x + 255) & ~(size_t)255; };
    char* p = (char*)d_ws;
    int*   cnt  = (int*)p;   p += alignup((size_t)L * 4);
    int*   off  = (int*)p;   p += alignup((size_t)L * 4);
    int*   bsum = (int*)p;   p += alignup(4096 * 4);
    int*   ent  = (int*)p;   p += alignup((size_t)KN * 4);
    short* W1t  = (short*)p; p += alignup((size_t)KOFF * CDIM * CDIM * 2);
    short* W2t  = (short*)p; p += alignup((size_t)KOFF * CDIM * CDIM * 2);
    short* h1b  = (short*)p;                         // n*128 bf16 = 128 MB

    // rulebook
    hipMemsetAsync(cnt, 0, (size_t)L * 4, stream);
    wconv_kernel<<<(KOFF * CDIM * CDIM + 255) / 256, 256, 0, stream>>>(W1, W2, W1t, W2t);
    count_kernel<<<(KN + 255) / 256, 256, 0, stream>>>(out_idx, mask, cnt, n, KN);
    scan_p1<<<NB, 256, 0, stream>>>(cnt, bsum, L);
    scan_p2<<<1, 1024, 0, stream>>>(bsum, NB);
    scan_p3<<<NB, 256, 0, stream>>>(cnt, bsum, off, L);
    fill_kernel<<<(KN + 255) / 256, 256, 0, stream>>>(out_idx, in_idx, mask, off, ent, n, KN);

    // fused convs
    const int nblk = (n + 63) / 64;
    conv_csr_kernel<0><<<nblk, 256, 0, stream>>>(
        feat, W1t, off, ent, gamma1, beta1, mean1, var1, nullptr, h1b, n);
    conv_csr_kernel<1><<<nblk, 256, 0, stream>>>(
        h1b, W2t, off, ent, gamma2, beta2, mean2, var2, feat, d_out, n);
}

// Round 4
// 836.022 us; speedup vs baseline: 1.9497x; 1.9497x over previous
//
#include <hip/hip_runtime.h>

#define CDIM 128
#define KOFF 4
#define EPS 1e-4f
#define SCAN_CHUNK 2048   // 256 threads * 8 elems
#define ROWS 32           // output rows per block

typedef __attribute__((ext_vector_type(8))) short bf16x8;
typedef __attribute__((ext_vector_type(4))) float f32x4;

__device__ __forceinline__ unsigned short f2bf(float f) {
    unsigned int u = __builtin_bit_cast(unsigned int, f);
    u += 0x7fffu + ((u >> 16) & 1u);          // round-to-nearest-even
    return (unsigned short)(u >> 16);
}
__device__ __forceinline__ float bf2f(unsigned short h) {
    unsigned int u = ((unsigned int)h) << 16;
    return __builtin_bit_cast(float, u);
}

// ---------------------------------------------------------------------------
// W convert+transpose: Wt[k][cout][cin] = bf16(W[k][cin][cout])
// ---------------------------------------------------------------------------
__global__ __launch_bounds__(256) void wconv_kernel(
    const float* __restrict__ W1, const float* __restrict__ W2,
    short* __restrict__ W1t, short* __restrict__ W2t)
{
    int idx = blockIdx.x * 256 + threadIdx.x;       // [k][co][ci]
    if (idx >= KOFF * CDIM * CDIM) return;
    int ci = idx & (CDIM - 1);
    int co = (idx >> 7) & (CDIM - 1);
    int k  = idx >> 14;
    size_t src = (size_t)k * CDIM * CDIM + (size_t)ci * CDIM + co;
    W1t[idx] = (short)f2bf(W1[src]);
    W2t[idx] = (short)f2bf(W2[src]);
}

// ---------------------------------------------------------------------------
// Rulebook: count -> scan -> fill.  Entry = src | (jloc<<19), jloc = j & 31.
// ---------------------------------------------------------------------------
__global__ __launch_bounds__(256) void count_kernel(
    const int* __restrict__ out_idx, const int* __restrict__ mask,
    int* __restrict__ cnt, int n, int KN)
{
    int t = blockIdx.x * 256 + threadIdx.x;
    if (t >= KN) return;
    if (mask[t]) {
        int k = t / n;
        atomicAdd(&cnt[(size_t)k * n + out_idx[t]], 1);
    }
}

__global__ __launch_bounds__(256) void scan_p1(
    const int* __restrict__ in, int* __restrict__ bsum, int L)
{
    __shared__ int red[256];
    int base = blockIdx.x * SCAN_CHUNK;
    int s = 0;
    #pragma unroll
    for (int u = 0; u < 8; ++u) {
        int i = base + u * 256 + threadIdx.x;
        if (i < L) s += in[i];
    }
    red[threadIdx.x] = s;
    __syncthreads();
    for (int d = 128; d > 0; d >>= 1) {
        if (threadIdx.x < d) red[threadIdx.x] += red[threadIdx.x + d];
        __syncthreads();
    }
    if (threadIdx.x == 0) bsum[blockIdx.x] = red[0];
}

__global__ __launch_bounds__(1024) void scan_p2(int* __restrict__ bsum, int NB)
{
    __shared__ int s[1024];
    int t = threadIdx.x;
    s[t] = (t < NB) ? bsum[t] : 0;
    __syncthreads();
    for (int d = 1; d < 1024; d <<= 1) {
        int x = s[t];
        if (t >= d) x += s[t - d];
        __syncthreads();
        s[t] = x;
        __syncthreads();
    }
    if (t < NB) bsum[t] = (t == 0) ? 0 : s[t - 1];   // exclusive
}

__global__ __launch_bounds__(256) void scan_p3(
    const int* __restrict__ in, const int* __restrict__ bsum,
    int* __restrict__ out, int L)
{
    __shared__ int ts[256];
    int t = threadIdx.x;
    int base = blockIdx.x * SCAN_CHUNK + t * 8;
    int v[8]; int s = 0;
    #pragma unroll
    for (int u = 0; u < 8; ++u) {
        int i = base + u;
        v[u] = (i < L) ? in[i] : 0;
        s += v[u];
    }
    ts[t] = s;
    __syncthreads();
    for (int d = 1; d < 256; d <<= 1) {
        int x = ts[t];
        if (t >= d) x += ts[t - d];
        __syncthreads();
        ts[t] = x;
        __syncthreads();
    }
    int pre = bsum[blockIdx.x] + ((t == 0) ? 0 : ts[t - 1]);
    #pragma unroll
    for (int u = 0; u < 8; ++u) {
        int i = base + u;
        if (i < L) { out[i] = pre; pre += v[u]; }
    }
}

__global__ __launch_bounds__(256) void fill_kernel(
    const int* __restrict__ out_idx, const int* __restrict__ in_idx,
    const int* __restrict__ mask, int* __restrict__ off,
    int* __restrict__ ent, int n, int KN)
{
    int t = blockIdx.x * 256 + threadIdx.x;
    if (t >= KN) return;
    if (mask[t]) {
        int k = t / n;
        int j = out_idx[t];
        int pos = atomicAdd(&off[(size_t)k * n + j], 1);
        ent[pos] = in_idx[t] | ((j & (ROWS - 1)) << 19);
    }
}
// post-fill: off[x] = END of bucket x; start = (x==0) ? 0 : off[x-1]

// ---------------------------------------------------------------------------
// Dense-tile conv: block owns 32 output rows.
//  phase 1: per-thread bucket sum (j,k,32ch slice) -> bf16 A-tile [32][512] LDS
//  phase 2: dense GEMM 32x512 @ 512x128 (merged K over 4 offsets), acc in regs
//  phase 3: fused BN epilogue through LDS, dense coalesced store
//  EPI=0: X=f32, out = bf16(relu(bn(.)))   EPI=1: X=bf16, out = bn(.)+feat f32
// ---------------------------------------------------------------------------
template <int EPI>
__global__ __launch_bounds__(256) void conv_csr_kernel(
    const void* __restrict__ Xv, const short* __restrict__ Wt,
    const int* __restrict__ off, const int* __restrict__ ent,
    const float* __restrict__ gamma, const float* __restrict__ beta,
    const float* __restrict__ mean, const float* __restrict__ var,
    const float* __restrict__ feat, void* __restrict__ Yv, int n)
{
    const int j0 = blockIdx.x * ROWS;
    const int t  = threadIdx.x;

    __shared__ alignas(16) short Ab[ROWS * 512];     // 32 KB bf16 A-tile (swizzled)
    __shared__ alignas(16) float s_scale[CDIM], s_shift[CDIM];

    if (t < CDIM) {
        float sc = gamma[t] * rsqrtf(var[t] + EPS);
        s_scale[t] = sc;
        s_shift[t] = beta[t] - mean[t] * sc;
    }

    // ---- phase 1: bucket-sum gather. slot s = bucket*4 + chgroup ----
    #pragma unroll
    for (int ss = 0; ss < 2; ++ss) {
        int s  = t + ss * 256;          // 0..511
        int b  = s >> 2;                // bucket 0..127
        int cg = s & 3;                 // 32-channel group
        int k  = b >> 5;
        int jl = b & (ROWS - 1);
        int e0 = 0, e1 = 0;
        if (j0 + jl < n) {
            size_t x = (size_t)k * n + j0 + jl;
            e0 = (x == 0) ? 0 : off[x - 1];
            e1 = off[x];
        }
        float acc[32];
        #pragma unroll
        for (int c = 0; c < 32; ++c) acc[c] = 0.f;
        for (int e = e0; e < e1; ++e) {
            int src = ent[e] & 0x7FFFF;
            if (EPI == 0) {
                const float4* xr = (const float4*)Xv + (size_t)src * 32 + cg * 8;
                #pragma unroll
                for (int u = 0; u < 8; ++u) {
                    float4 v = xr[u];
                    acc[u * 4 + 0] += v.x; acc[u * 4 + 1] += v.y;
                    acc[u * 4 + 2] += v.z; acc[u * 4 + 3] += v.w;
                }
            } else {
                const bf16x8* xr = (const bf16x8*)((const short*)Xv + (size_t)src * CDIM + cg * 32);
                #pragma unroll
                for (int u = 0; u < 4; ++u) {
                    bf16x8 v = xr[u];
                    #pragma unroll
                    for (int q = 0; q < 8; ++q)
                        acc[u * 8 + q] += bf2f((unsigned short)v[q]);
                }
            }
        }
        // write 4 bf16 chunks, chunk-swizzled: slot = c ^ (row&7)
        #pragma unroll
        for (int u = 0; u < 4; ++u) {
            int c = k * 16 + cg * 4 + u;         // chunk col 0..63
            bf16x8 v;
            #pragma unroll
            for (int q = 0; q < 8; ++q) v[q] = (short)f2bf(acc[u * 8 + q]);
            *(bf16x8*)(Ab + jl * 512 + ((c ^ (jl & 7)) << 3)) = v;
        }
    }
    __syncthreads();

    // ---- phase 2: dense GEMM. wave w: cols w*32..+31, rows 0..31 ----
    const int w    = t >> 6;
    const int lane = t & 63;
    const int lrow = lane & 15;
    const int g    = lane >> 4;

    f32x4 acc[2][2];   // [m][nt]
    #pragma unroll
    for (int m = 0; m < 2; ++m)
        #pragma unroll
        for (int nt = 0; nt < 2; ++nt) acc[m][nt] = (f32x4){0.f, 0.f, 0.f, 0.f};

    #pragma unroll
    for (int kb = 0; kb < 16; ++kb) {
        int k  = kb >> 2;
        int kk = kb & 3;
        const short* Wk = Wt + (size_t)k * CDIM * CDIM + kk * 32 + g * 8;
        bf16x8 b0 = *(const bf16x8*)(Wk + (w * 32 + lrow) * CDIM);
        bf16x8 b1 = *(const bf16x8*)(Wk + (w * 32 + 16 + lrow) * CDIM);
        int c = kb * 4 + g;
        bf16x8 a0 = *(const bf16x8*)(Ab + lrow * 512 + ((c ^ (lrow & 7)) << 3));
        bf16x8 a1 = *(const bf16x8*)(Ab + (16 + lrow) * 512 + ((c ^ (lrow & 7)) << 3));
        acc[0][0] = __builtin_amdgcn_mfma_f32_16x16x32_bf16(a0, b0, acc[0][0], 0, 0, 0);
        acc[0][1] = __builtin_amdgcn_mfma_f32_16x16x32_bf16(a0, b1, acc[0][1], 0, 0, 0);
        acc[1][0] = __builtin_amdgcn_mfma_f32_16x16x32_bf16(a1, b0, acc[1][0], 0, 0, 0);
        acc[1][1] = __builtin_amdgcn_mfma_f32_16x16x32_bf16(a1, b1, acc[1][1], 0, 0, 0);
    }
    __syncthreads();      // all Ab reads done before reuse as f32 out-tile

    // ---- phase 3: acc -> LDS f32 out-tile (reuse Ab), fused BN store ----
    float* Ot = (float*)Ab;               // [32][128] f32 = 16 KB
    #pragma unroll
    for (int m = 0; m < 2; ++m)
        #pragma unroll
        for (int nt = 0; nt < 2; ++nt)
            #pragma unroll
            for (int j = 0; j < 4; ++j) {
                int row = m * 16 + g * 4 + j;
                int col = w * 32 + nt * 16 + lrow;
                Ot[row * CDIM + col] = acc[m][nt][j];
            }
    __syncthreads();

    const int jrows = min(ROWS, n - j0);
    #pragma unroll
    for (int u = 0; u < 4; ++u) {
        int idx = u * 256 + t;            // 0..1023 = 32 rows * 32 float4
        int row = idx >> 5, c4 = idx & 31;
        if (row < jrows) {
            float4 x  = ((const float4*)Ot)[idx];
            float4 sc = ((const float4*)s_scale)[c4];
            float4 sh = ((const float4*)s_shift)[c4];
            size_t go = (size_t)(j0 + row) * 32 + c4;
            if (EPI == 0) {
                ushort4 o;
                o.x = f2bf(fmaxf(x.x * sc.x + sh.x, 0.f));
                o.y = f2bf(fmaxf(x.y * sc.y + sh.y, 0.f));
                o.z = f2bf(fmaxf(x.z * sc.z + sh.z, 0.f));
                o.w = f2bf(fmaxf(x.w * sc.w + sh.w, 0.f));
                ((ushort4*)Yv)[go] = o;
            } else {
                float4 f = ((const float4*)feat)[go];
                float4 r;
                r.x = x.x * sc.x + sh.x + f.x;
                r.y = x.y * sc.y + sh.y + f.y;
                r.z = x.z * sc.z + sh.z + f.z;
                r.w = x.w * sc.w + sh.w + f.w;
                ((float4*)Yv)[go] = r;
            }
        }
    }
}

extern "C" void kernel_launch(void* const* d_in, const int* in_sizes, int n_in,
                              void* d_out, int out_size, void* d_ws, size_t ws_size,
                              hipStream_t stream)
{
    const float* feat   = (const float*)d_in[0];
    const float* W1     = (const float*)d_in[1];
    const float* W2     = (const float*)d_in[2];
    const float* gamma1 = (const float*)d_in[3];
    const float* beta1  = (const float*)d_in[4];
    const float* mean1  = (const float*)d_in[5];
    const float* var1   = (const float*)d_in[6];
    const float* gamma2 = (const float*)d_in[7];
    const float* beta2  = (const float*)d_in[8];
    const float* mean2  = (const float*)d_in[9];
    const float* var2   = (const float*)d_in[10];
    const int* in_idx   = (const int*)d_in[11];
    const int* out_idx  = (const int*)d_in[12];
    const int* mask     = (const int*)d_in[13];

    const int n  = in_sizes[0] / CDIM;     // 500000 (< 2^19 for entry packing)
    const int KN = KOFF * n;
    const int L  = KN + 1;
    const int NB = (L + SCAN_CHUNK - 1) / SCAN_CHUNK;   // 977 <= 1024

    auto alignup = [](size_t x) { return (x + 255) & ~(size_t)255; };
    char* p = (char*)d_ws;
    int*   cnt  = (int*)p;   p += alignup((size_t)L * 4);
    int*   off  = (int*)p;   p += alignup((size_t)L * 4);
    int*   bsum = (int*)p;   p += alignup(4096 * 4);
    int*   ent  = (int*)p;   p += alignup((size_t)KN * 4);
    short* W1t  = (short*)p; p += alignup((size_t)KOFF * CDIM * CDIM * 2);
    short* W2t  = (short*)p; p += alignup((size_t)KOFF * CDIM * CDIM * 2);
    short* h1b  = (short*)p;                         // n*128 bf16 = 128 MB

    // rulebook
    hipMemsetAsync(cnt, 0, (size_t)L * 4, stream);
    wconv_kernel<<<(KOFF * CDIM * CDIM + 255) / 256, 256, 0, stream>>>(W1, W2, W1t, W2t);
    count_kernel<<<(KN + 255) / 256, 256, 0, stream>>>(out_idx, mask, cnt, n, KN);
    scan_p1<<<NB, 256, 0, stream>>>(cnt, bsum, L);
    scan_p2<<<1, 1024, 0, stream>>>(bsum, NB);
    scan_p3<<<NB, 256, 0, stream>>>(cnt, bsum, off, L);
    fill_kernel<<<(KN + 255) / 256, 256, 0, stream>>>(out_idx, in_idx, mask, off, ent, n, KN);

    // fused convs (dense-tile GEMM form)
    const int nblk = (n + ROWS - 1) / ROWS;
    conv_csr_kernel<0><<<nblk, 256, 0, stream>>>(
        feat, W1t, off, ent, gamma1, beta1, mean1, var1, nullptr, h1b, n);
    conv_csr_kernel<1><<<nblk, 256, 0, stream>>>(
        h1b, W2t, off, ent, gamma2, beta2, mean2, var2, feat, d_out, n);
}